// Round 1
// baseline (863.525 us; speedup 1.0000x reference)
//
#include <hip/hip_runtime.h>
#include <hip/hip_bf16.h>

// Problem constants (fixed by setup_inputs)
#define BB   32      // batch
#define TT   4096    // seq len
#define CTXD 1024    // encoder hidden (K of the big GEMM)
#define HH   256     // attention hidden (N of the big GEMM)
#define DH   512     // decoder hidden
#define BT   64      // t-rows per block
#define NTILES (TT/BT)  // 64 tiles per batch
#define BK   64      // K-chunk staged in LDS
#define LDA  72      // padded LDS row stride in bf16 elems (144 B = 9*16B, 2-way-bank only)

typedef __attribute__((ext_vector_type(8))) short bf16x8;
typedef __attribute__((ext_vector_type(4))) float f32x4;

static __device__ __forceinline__ unsigned short f2bf(float f) {
    unsigned int u = __float_as_uint(f);
    u += 0x7FFF + ((u >> 16) & 1);   // round-to-nearest-even
    return (unsigned short)(u >> 16);
}

// ---- prep: U_w fp32 -> bf16 (row-major [H][CTX]) ----
__global__ void uconv_kernel(const float* __restrict__ Uw, unsigned short* __restrict__ Ub) {
    int idx = blockIdx.x * blockDim.x + threadIdx.x;  // 65536 threads, 4 elems each
    float4 u4 = ((const float4*)Uw)[idx];
    ushort4 o;
    o.x = f2bf(u4.x); o.y = f2bf(u4.y); o.z = f2bf(u4.z); o.w = f2bf(u4.w);
    ((ushort4*)Ub)[idx] = o;
}

// ---- prep: bias[b,h] = prev[b,:]·W_w[h,:] + W_b[h] + U_b[h] (full fp32) ----
__global__ void bias_kernel(const float* __restrict__ prev, const float* __restrict__ Ww,
                            const float* __restrict__ Wb, const float* __restrict__ Ubias,
                            float* __restrict__ bias) {
    __shared__ float ps[DH];
    int b = blockIdx.x, h = threadIdx.x;
    if (h < DH / 4) ((float4*)ps)[h] = ((const float4*)(prev + (size_t)b * DH))[h];
    __syncthreads();
    float acc = Wb[h] + Ubias[h];
    const float4* wr = (const float4*)(Ww + (size_t)h * DH);
    #pragma unroll 4
    for (int d = 0; d < DH / 4; ++d) {
        float4 w4 = wr[d];
        float4 p4 = ((const float4*)ps)[d];
        acc += w4.x * p4.x + w4.y * p4.y + w4.z * p4.z + w4.w * p4.w;
    }
    bias[b * HH + h] = acc;
}

// ---- main: per (b, 64-t tile): bf16 MFMA scores -> relu·v -> local softmax -> partial context ----
__global__ void attn_main(const float* __restrict__ enc, const unsigned short* __restrict__ Ub,
                          const float* __restrict__ bias, const float* __restrict__ v,
                          float* __restrict__ partO, float* __restrict__ partM,
                          float* __restrict__ partL) {
    __shared__ __align__(16) unsigned short As[BT * LDA];   //  9216 B
    __shared__ __align__(16) unsigned short Us[HH * LDA];   // 36864 B
    __shared__ float epart[4][BT];
    __shared__ float pbuf[BT];

    const int tid  = threadIdx.x;
    const int lane = tid & 63;
    const int w    = tid >> 6;         // wave 0..3 -> N columns [64w, 64w+64)
    const int quad = lane >> 4;
    const int l15  = lane & 15;
    const int b    = blockIdx.x & 31;
    const int tile = blockIdx.x >> 5;
    const int t0   = tile * BT;
    const int pi   = b * NTILES + tile;

    const float* encBase = enc + ((size_t)b * TT + t0) * CTXD;

    f32x4 acc[4][4];
    #pragma unroll
    for (int mi = 0; mi < 4; ++mi)
        #pragma unroll
        for (int ni = 0; ni < 4; ++ni) acc[mi][ni] = (f32x4){0.f, 0.f, 0.f, 0.f};

    const int arow = tid >> 4;   // A staging: 16 rows/pass, 16 float4 per row
    const int acg  = tid & 15;

    for (int kt = 0; kt < CTXD / BK; ++kt) {
        // stage enc tile (fp32 -> bf16): 64 rows x 64 k
        const float* ga = encBase + kt * BK;
        #pragma unroll
        for (int rr = 0; rr < 4; ++rr) {
            int row = arow + rr * 16;
            float4 a4 = *(const float4*)(ga + (size_t)row * CTXD + acg * 4);
            ushort4 o;
            o.x = f2bf(a4.x); o.y = f2bf(a4.y); o.z = f2bf(a4.z); o.w = f2bf(a4.w);
            *(ushort4*)&As[row * LDA + acg * 4] = o;
        }
        // stage U tile (bf16): 256 rows x 64 k
        #pragma unroll
        for (int ii = 0; ii < 8; ++ii) {
            int idx = ii * 256 + tid;
            int row = idx >> 3;
            int g   = idx & 7;
            uint4 u = *(const uint4*)(Ub + (size_t)row * CTXD + kt * BK + g * 8);
            *(uint4*)&Us[row * LDA + g * 8] = u;
        }
        __syncthreads();
        #pragma unroll
        for (int ks = 0; ks < BK / 32; ++ks) {
            bf16x8 af[4], bfr[4];
            #pragma unroll
            for (int mi = 0; mi < 4; ++mi)
                af[mi] = *(const bf16x8*)&As[(mi * 16 + l15) * LDA + ks * 32 + quad * 8];
            #pragma unroll
            for (int ni = 0; ni < 4; ++ni)
                bfr[ni] = *(const bf16x8*)&Us[(w * 64 + ni * 16 + l15) * LDA + ks * 32 + quad * 8];
            #pragma unroll
            for (int mi = 0; mi < 4; ++mi)
                #pragma unroll
                for (int ni = 0; ni < 4; ++ni)
                    acc[mi][ni] = __builtin_amdgcn_mfma_f32_16x16x32_bf16(af[mi], bfr[ni], acc[mi][ni], 0, 0, 0);
        }
        __syncthreads();
    }

    // epilogue: energy[t] = sum_h relu(S[t,h] + bias[b,h]) * v[h]
    float vv[4], bb[4];
    #pragma unroll
    for (int ni = 0; ni < 4; ++ni) {
        int h = w * 64 + ni * 16 + l15;
        vv[ni] = v[h];
        bb[ni] = bias[b * HH + h];
    }
    #pragma unroll
    for (int mi = 0; mi < 4; ++mi) {
        #pragma unroll
        for (int r = 0; r < 4; ++r) {
            float e = 0.f;
            #pragma unroll
            for (int ni = 0; ni < 4; ++ni) {
                float x = acc[mi][ni][r] + bb[ni];
                e += fmaxf(x, 0.f) * vv[ni];
            }
            // reduce over 16 cols held in the quad
            e += __shfl_xor(e, 1);
            e += __shfl_xor(e, 2);
            e += __shfl_xor(e, 4);
            e += __shfl_xor(e, 8);
            if (l15 == 0) epart[w][mi * 16 + quad * 4 + r] = e;
        }
    }
    __syncthreads();

    // block softmax (local m,l) by wave 0
    if (tid < 64) {
        float e = epart[0][tid] + epart[1][tid] + epart[2][tid] + epart[3][tid];
        float m = e;
        #pragma unroll
        for (int off = 32; off; off >>= 1) m = fmaxf(m, __shfl_xor(m, off));
        float p = __expf(e - m);
        float l = p;
        #pragma unroll
        for (int off = 32; off; off >>= 1) l += __shfl_xor(l, off);
        pbuf[tid] = p;
        if (tid == 0) { partM[pi] = m; partL[pi] = l; }
    }
    __syncthreads();

    // partial context: o[c] = sum_t p[t] * enc[b, t0+t, c]  (tile should be L2-warm)
    float4 o4 = {0.f, 0.f, 0.f, 0.f};
    #pragma unroll 4
    for (int t = 0; t < BT; ++t) {
        float p = pbuf[t];
        float4 ev = *(const float4*)(encBase + (size_t)t * CTXD + tid * 4);
        o4.x += p * ev.x; o4.y += p * ev.y; o4.z += p * ev.z; o4.w += p * ev.w;
    }
    *(float4*)(partO + (size_t)pi * CTXD + tid * 4) = o4;
}

// ---- combine: per batch merge 64 (o,m,l) partials ----
__global__ void combine_kernel(const float* __restrict__ partO, const float* __restrict__ partM,
                               const float* __restrict__ partL, float* __restrict__ out) {
    __shared__ float sc[NTILES];
    __shared__ float sL;
    int b = blockIdx.x, tid = threadIdx.x;
    if (tid < 64) {
        float m = partM[b * NTILES + tid];
        float l = partL[b * NTILES + tid];
        float M = m;
        #pragma unroll
        for (int off = 32; off; off >>= 1) M = fmaxf(M, __shfl_xor(M, off));
        float s = __expf(m - M);
        sc[tid] = s;
        float Lp = l * s;
        #pragma unroll
        for (int off = 32; off; off >>= 1) Lp += __shfl_xor(Lp, off);
        if (tid == 0) sL = Lp;
    }
    __syncthreads();
    float4 o = {0.f, 0.f, 0.f, 0.f};
    const float* base = partO + (size_t)b * NTILES * CTXD;
    #pragma unroll 4
    for (int i = 0; i < NTILES; ++i) {
        float s = sc[i];
        float4 p4 = *(const float4*)(base + (size_t)i * CTXD + tid * 4);
        o.x += s * p4.x; o.y += s * p4.y; o.z += s * p4.z; o.w += s * p4.w;
    }
    float inv = 1.0f / sL;
    float4 r; r.x = o.x * inv; r.y = o.y * inv; r.z = o.z * inv; r.w = o.w * inv;
    ((float4*)out)[b * (CTXD / 4) + tid] = r;
}

extern "C" void kernel_launch(void* const* d_in, const int* in_sizes, int n_in,
                              void* d_out, int out_size, void* d_ws, size_t ws_size,
                              hipStream_t stream) {
    const float* prev  = (const float*)d_in[2];   // [32,1,512]
    const float* enc   = (const float*)d_in[3];   // [32,4096,1024]
    const float* Ww    = (const float*)d_in[4];   // [256,512]
    const float* Wb    = (const float*)d_in[5];   // [256]
    const float* Uw    = (const float*)d_in[6];   // [256,1024]
    const float* Ubias = (const float*)d_in[7];   // [256]
    const float* v     = (const float*)d_in[8];   // [256]
    float* out = (float*)d_out;                   // [32,1024]

    char* ws = (char*)d_ws;
    float* bias          = (float*)ws;                          // 32 KB
    unsigned short* Ub   = (unsigned short*)(ws + 32768);       // 512 KB
    float* partO         = (float*)(ws + 32768 + 524288);       // 8 MB
    float* partM         = partO + (size_t)BB * NTILES * CTXD;  // 8 KB
    float* partL         = partM + BB * NTILES;                 // 8 KB

    uconv_kernel<<<dim3(256), dim3(256), 0, stream>>>(Uw, Ub);
    bias_kernel<<<dim3(BB), dim3(HH), 0, stream>>>(prev, Ww, Wb, Ubias, bias);
    attn_main<<<dim3(BB * NTILES), dim3(256), 0, stream>>>(enc, Ub, bias, v, partO, partM, partL);
    combine_kernel<<<dim3(BB), dim3(256), 0, stream>>>(partO, partM, partL, out);
}